// Round 1
// baseline (1638.643 us; speedup 1.0000x reference)
//
#include <hip/hip_runtime.h>

// GraphSAGE 2-layer, N=50000, E=800000, 64 -> 128 -> 64, fp32.
//   h   = relu(mean_agg(x) @ W1_l + b1 + x @ W1_r)
//   out = mean_agg(h) @ W2_l + b2 + h @ W2_r
// Linearity trick: mean_agg(h) @ W2_l == agg(h @ W2_l)/cnt, so we scatter
// p = h @ W2_l (width 64) instead of h (width 128).

#define GNN_N 50000
#define GNN_E 800000

// ---------------------------------------------------------------------------
// scatter: for each edge e, agg[dst[e]] += feat[src[e]] (feat width 64 f32).
// 16 threads per edge, float4 per thread. Optionally counts degree.
// ---------------------------------------------------------------------------
__global__ __launch_bounds__(256) void gnn_scatter(
    const int* __restrict__ src, const int* __restrict__ dst,
    const float* __restrict__ feat, float* __restrict__ agg,
    float* __restrict__ cnt, int E) {
  int t = blockIdx.x * blockDim.x + threadIdx.x;
  int e = t >> 4;
  if (e >= E) return;
  int c4 = (t & 15) << 2;  // feature offset 0,4,...,60
  int s = src[e];
  int d = dst[e];
  const float4 v =
      *reinterpret_cast<const float4*>(feat + (size_t)s * 64 + c4);
  float* a = agg + (size_t)d * 64 + c4;
  atomicAdd(a + 0, v.x);
  atomicAdd(a + 1, v.y);
  atomicAdd(a + 2, v.z);
  atomicAdd(a + 3, v.w);
  if (cnt != nullptr && (t & 15) == 0) atomicAdd(cnt + d, 1.0f);
}

// ---------------------------------------------------------------------------
// dense1: per node i (one block, 128 threads):
//   mean = agg1[i]/max(cnt,1)
//   h[i][j]  = relu(b1[j] + sum_k mean[k]*W1l[k][j] + x[i][k]*W1r[k][j])
//   p[i][j2] = sum_k h[i][k]*W2l[k][j2]            (j2 < 64)
// ---------------------------------------------------------------------------
__global__ __launch_bounds__(128) void gnn_dense1(
    const float* __restrict__ x, const float* __restrict__ agg1,
    const float* __restrict__ cnt, const float* __restrict__ W1l,
    const float* __restrict__ b1, const float* __restrict__ W1r,
    const float* __restrict__ W2l, float* __restrict__ h,
    float* __restrict__ p) {
  int i = blockIdx.x;
  int j = threadIdx.x;  // 0..127
  __shared__ float xs[64];
  __shared__ float ms[64];
  __shared__ float hs[128];
  if (j < 64) {
    xs[j] = x[(size_t)i * 64 + j];
    float c = cnt[i];
    c = fmaxf(c, 1.0f);
    ms[j] = agg1[(size_t)i * 64 + j] / c;
  }
  __syncthreads();
  float acc = b1[j];
#pragma unroll
  for (int k = 0; k < 64; ++k) {
    acc += ms[k] * W1l[k * 128 + j];
    acc += xs[k] * W1r[k * 128 + j];
  }
  acc = fmaxf(acc, 0.0f);
  h[(size_t)i * 128 + j] = acc;
  hs[j] = acc;
  __syncthreads();
  if (j < 64) {
    float a2 = 0.0f;
#pragma unroll
    for (int k = 0; k < 128; ++k) a2 += hs[k] * W2l[k * 64 + j];
    p[(size_t)i * 64 + j] = a2;
  }
}

// ---------------------------------------------------------------------------
// dense2: out[i][j] = agg2[i][j]/max(cnt,1) + b2[j] + sum_k h[i][k]*W2r[k][j]
// one block (64 threads) per node.
// ---------------------------------------------------------------------------
__global__ __launch_bounds__(64) void gnn_dense2(
    const float* __restrict__ h, const float* __restrict__ agg2,
    const float* __restrict__ cnt, const float* __restrict__ W2r,
    const float* __restrict__ b2, float* __restrict__ out) {
  int i = blockIdx.x;
  int j = threadIdx.x;  // 0..63
  __shared__ float hs[128];
  hs[j] = h[(size_t)i * 128 + j];
  hs[j + 64] = h[(size_t)i * 128 + 64 + j];
  __syncthreads();
  float c = fmaxf(cnt[i], 1.0f);
  float acc = agg2[(size_t)i * 64 + j] / c + b2[j];
#pragma unroll
  for (int k = 0; k < 128; ++k) acc += hs[k] * W2r[k * 64 + j];
  out[(size_t)i * 64 + j] = acc;
}

extern "C" void kernel_launch(void* const* d_in, const int* in_sizes, int n_in,
                              void* d_out, int out_size, void* d_ws,
                              size_t ws_size, hipStream_t stream) {
  const float* x = (const float*)d_in[0];
  const int* ei = (const int*)d_in[1];
  const float* W1l = (const float*)d_in[2];
  const float* b1 = (const float*)d_in[3];
  const float* W1r = (const float*)d_in[4];
  const float* W2l = (const float*)d_in[5];
  const float* b2 = (const float*)d_in[6];
  const float* W2r = (const float*)d_in[7];
  float* out = (float*)d_out;

  const int N = in_sizes[0] / 64;   // 50000
  const int E = in_sizes[1] / 2;    // 800000

  // workspace layout (floats): cnt[N] | agg[N*64] | h[N*128] | p[N*64]
  float* cnt = (float*)d_ws;
  float* agg = cnt + N;
  float* h = agg + (size_t)N * 64;
  float* p = h + (size_t)N * 128;

  const int* src = ei;
  const int* dst = ei + E;

  // zero cnt + agg (poisoned 0xAA before every call)
  hipMemsetAsync(d_ws, 0, (size_t)(N + (size_t)N * 64) * sizeof(float),
                 stream);

  dim3 sblk(256);
  dim3 sgrid((unsigned)(((size_t)E * 16 + 255) / 256));

  // layer 1 aggregation of x (+ degree count)
  gnn_scatter<<<sgrid, sblk, 0, stream>>>(src, dst, x, agg, cnt, E);
  // layer 1 dense + fused p = h @ W2_l
  gnn_dense1<<<N, 128, 0, stream>>>(x, agg, cnt, W1l, b1, W1r, W2l, h, p);
  // re-zero agg for layer 2
  hipMemsetAsync(agg, 0, (size_t)N * 64 * sizeof(float), stream);
  // layer 2 aggregation of p
  gnn_scatter<<<sgrid, sblk, 0, stream>>>(src, dst, p, agg, nullptr, E);
  // layer 2 dense
  gnn_dense2<<<N, 64, 0, stream>>>(h, agg, cnt, W2r, b2, out);
}

// Round 2
// 1215.991 us; speedup vs baseline: 1.3476x; 1.3476x over previous
//
#include <hip/hip_runtime.h>

// GraphSAGE 2-layer, N=50000, E=800000, 64 -> 128 -> 64, fp32.
//   h   = relu(mean_agg(x) @ W1_l + b1 + x @ W1_r)
//   out = mean_agg(h) @ W2_l + b2 + h @ W2_r
// R2: replace float-atomic scatter (825MB WRITE_SIZE, 695us each) with
// on-device CSR build (int atomics on 200KB) + gather-based aggregation,
// fused with the dense layers. Linearity: mean_agg(h)@W2_l = agg(h@W2_l)/cnt,
// so layer-2 aggregates p = h@W2_l (width 64), not h (width 128).

#define SCAN_B 256

// ---------------------------------------------------------------------------
// CSR build step 1: degree histogram over dst.
// ---------------------------------------------------------------------------
__global__ __launch_bounds__(256) void k_hist(const int* __restrict__ dst,
                                              int* __restrict__ deg, int E) {
  int e = blockIdx.x * blockDim.x + threadIdx.x;
  if (e < E) atomicAdd(&deg[dst[e]], 1);
}

// step 2a: per-block exclusive scan of deg -> rowptr (partial), block sums.
__global__ __launch_bounds__(SCAN_B) void k_scan1(const int* __restrict__ deg,
                                                  int* __restrict__ rowptr,
                                                  int* __restrict__ bsum,
                                                  int N) {
  __shared__ int s[SCAN_B];
  int t = threadIdx.x;
  int gid = blockIdx.x * SCAN_B + t;
  int v = (gid < N) ? deg[gid] : 0;
  s[t] = v;
  __syncthreads();
  for (int off = 1; off < SCAN_B; off <<= 1) {
    int add = (t >= off) ? s[t - off] : 0;
    __syncthreads();
    s[t] += add;
    __syncthreads();
  }
  if (gid < N) rowptr[gid] = s[t] - v;  // exclusive, pre-offset
  if (t == SCAN_B - 1) bsum[blockIdx.x] = s[t];
}

// step 2b: single-block scan of block sums (NB <= 256).
__global__ __launch_bounds__(SCAN_B) void k_scan2(int* __restrict__ bsum,
                                                  int* __restrict__ rowptr,
                                                  int NB, int N) {
  __shared__ int s[SCAN_B];
  int t = threadIdx.x;
  int v = (t < NB) ? bsum[t] : 0;
  s[t] = v;
  __syncthreads();
  for (int off = 1; off < SCAN_B; off <<= 1) {
    int add = (t >= off) ? s[t - off] : 0;
    __syncthreads();
    s[t] += add;
    __syncthreads();
  }
  if (t < NB) bsum[t] = s[t] - v;                 // exclusive block offsets
  if (t == NB - 1) rowptr[N] = s[t];              // total = E
}

// step 2c: add block offsets; init fill cursors.
__global__ __launch_bounds__(SCAN_B) void k_scan3(int* __restrict__ rowptr,
                                                  const int* __restrict__ bsum,
                                                  int* __restrict__ pos,
                                                  int N) {
  int gid = blockIdx.x * SCAN_B + threadIdx.x;
  if (gid < N) {
    int r = rowptr[gid] + bsum[blockIdx.x];
    rowptr[gid] = r;
    pos[gid] = r;
  }
}

// step 3: bucket fill — colsrc[slot] = src[e], slot from per-dst cursor.
__global__ __launch_bounds__(256) void k_fill(const int* __restrict__ src,
                                              const int* __restrict__ dst,
                                              int* __restrict__ pos,
                                              int* __restrict__ colsrc, int E) {
  int e = blockIdx.x * blockDim.x + threadIdx.x;
  if (e >= E) return;
  int slot = atomicAdd(&pos[dst[e]], 1);
  colsrc[slot] = src[e];
}

// ---------------------------------------------------------------------------
// layer1: per 4 nodes (128 threads): gather mean of x over CSR neighbors,
//   h = relu(mean@W1l + b1 + x@W1r), p = h@W2l. Writes h [N,128], p [N,64].
// ---------------------------------------------------------------------------
__global__ __launch_bounds__(128) void k_layer1(
    const float* __restrict__ x, const int* __restrict__ rowptr,
    const int* __restrict__ colsrc, const float* __restrict__ W1l,
    const float* __restrict__ b1, const float* __restrict__ W1r,
    const float* __restrict__ W2l, float* __restrict__ h,
    float* __restrict__ p, int N) {
  int i0 = blockIdx.x * 4;
  int j = threadIdx.x;      // 0..127
  int jc = j & 63;
  __shared__ float ms[4][64];
  __shared__ float xs[4][64];
  __shared__ float hs[4][128];

  // gather: two passes, each pass wave0 -> node np*2, wave1 -> node np*2+1
  for (int np = 0; np < 2; ++np) {
    int n = np * 2 + (j >> 6);
    int node = i0 + n;
    float s = 0.f;
    float rdeg = 0.f;
    if (node < N) {
      int beg = rowptr[node], end = rowptr[node + 1];
      for (int e = beg; e < end; ++e)
        s += x[(size_t)colsrc[e] * 64 + jc];
      rdeg = 1.f / fmaxf((float)(end - beg), 1.f);
      xs[n][jc] = x[(size_t)node * 64 + jc];
    }
    ms[n][jc] = s * rdeg;
  }
  __syncthreads();

  // dense1: thread j owns output column j for all 4 nodes
  float a0 = b1[j], a1 = a0, a2 = a0, a3 = a0;
#pragma unroll
  for (int k = 0; k < 64; ++k) {
    float wl = W1l[k * 128 + j];
    float wr = W1r[k * 128 + j];
    a0 += ms[0][k] * wl + xs[0][k] * wr;
    a1 += ms[1][k] * wl + xs[1][k] * wr;
    a2 += ms[2][k] * wl + xs[2][k] * wr;
    a3 += ms[3][k] * wl + xs[3][k] * wr;
  }
  a0 = fmaxf(a0, 0.f); a1 = fmaxf(a1, 0.f);
  a2 = fmaxf(a2, 0.f); a3 = fmaxf(a3, 0.f);
  hs[0][j] = a0; hs[1][j] = a1; hs[2][j] = a2; hs[3][j] = a3;
  if (i0 + 0 < N) h[(size_t)(i0 + 0) * 128 + j] = a0;
  if (i0 + 1 < N) h[(size_t)(i0 + 1) * 128 + j] = a1;
  if (i0 + 2 < N) h[(size_t)(i0 + 2) * 128 + j] = a2;
  if (i0 + 3 < N) h[(size_t)(i0 + 3) * 128 + j] = a3;
  __syncthreads();

  // p = h @ W2l  (two passes over node pairs)
  for (int np = 0; np < 2; ++np) {
    int n = np * 2 + (j >> 6);
    int node = i0 + n;
    if (node >= N) continue;
    float a = 0.f;
#pragma unroll
    for (int k = 0; k < 128; ++k) a += hs[n][k] * W2l[k * 64 + jc];
    p[(size_t)node * 64 + jc] = a;
  }
}

// ---------------------------------------------------------------------------
// layer2: per 4 nodes: out = mean_agg(p) + b2 + h@W2r.
// ---------------------------------------------------------------------------
__global__ __launch_bounds__(128) void k_layer2(
    const float* __restrict__ h, const float* __restrict__ p,
    const int* __restrict__ rowptr, const int* __restrict__ colsrc,
    const float* __restrict__ W2r, const float* __restrict__ b2,
    float* __restrict__ out, int N) {
  int i0 = blockIdx.x * 4;
  int j = threadIdx.x;
  int jc = j & 63;
  __shared__ float ms[4][64];
  __shared__ float hs[4][128];

  for (int n = 0; n < 4; ++n) {
    int node = i0 + n;
    if (node < N) hs[n][j] = h[(size_t)node * 128 + j];
  }
  for (int np = 0; np < 2; ++np) {
    int n = np * 2 + (j >> 6);
    int node = i0 + n;
    float s = 0.f;
    float rdeg = 0.f;
    if (node < N) {
      int beg = rowptr[node], end = rowptr[node + 1];
      for (int e = beg; e < end; ++e)
        s += p[(size_t)colsrc[e] * 64 + jc];
      rdeg = 1.f / fmaxf((float)(end - beg), 1.f);
    }
    ms[n][jc] = s * rdeg;
  }
  __syncthreads();

  for (int np = 0; np < 2; ++np) {
    int n = np * 2 + (j >> 6);
    int node = i0 + n;
    if (node >= N) continue;
    float a = ms[n][jc] + b2[jc];
#pragma unroll
    for (int k = 0; k < 128; ++k) a += hs[n][k] * W2r[k * 64 + jc];
    out[(size_t)node * 64 + jc] = a;
  }
}

extern "C" void kernel_launch(void* const* d_in, const int* in_sizes, int n_in,
                              void* d_out, int out_size, void* d_ws,
                              size_t ws_size, hipStream_t stream) {
  const float* x = (const float*)d_in[0];
  const int* ei = (const int*)d_in[1];
  const float* W1l = (const float*)d_in[2];
  const float* b1 = (const float*)d_in[3];
  const float* W1r = (const float*)d_in[4];
  const float* W2l = (const float*)d_in[5];
  const float* b2 = (const float*)d_in[6];
  const float* W2r = (const float*)d_in[7];
  float* out = (float*)d_out;

  const int N = in_sizes[0] / 64;  // 50000
  const int E = in_sizes[1] / 2;   // 800000
  const int* src = ei;
  const int* dst = ei + E;

  // workspace layout:
  //   int deg[N] | int rowptr[N+1] | int pos[N] | int bsum[256] | int colsrc[E]
  //   | float h[N*128] | float p[N*64]
  int* deg = (int*)d_ws;
  int* rowptr = deg + N;
  int* pos = rowptr + (N + 1);
  int* bsum = pos + N;
  int* colsrc = bsum + 256;
  float* h = (float*)(colsrc + E);
  float* p = h + (size_t)N * 128;

  const int NB = (N + SCAN_B - 1) / SCAN_B;  // 196

  hipMemsetAsync(deg, 0, (size_t)N * sizeof(int), stream);
  k_hist<<<(E + 255) / 256, 256, 0, stream>>>(dst, deg, E);
  k_scan1<<<NB, SCAN_B, 0, stream>>>(deg, rowptr, bsum, N);
  k_scan2<<<1, SCAN_B, 0, stream>>>(bsum, rowptr, NB, N);
  k_scan3<<<NB, SCAN_B, 0, stream>>>(rowptr, bsum, pos, N);
  k_fill<<<(E + 255) / 256, 256, 0, stream>>>(src, dst, pos, colsrc, E);

  int nblk = (N + 3) / 4;  // 12500
  k_layer1<<<nblk, 128, 0, stream>>>(x, rowptr, colsrc, W1l, b1, W1r, W2l, h,
                                     p, N);
  k_layer2<<<nblk, 128, 0, stream>>>(h, p, rowptr, colsrc, W2r, b2, out, N);
}

// Round 4
// 462.098 us; speedup vs baseline: 3.5461x; 2.6315x over previous
//
#include <hip/hip_runtime.h>

// GraphSAGE 2-layer, N=50000, E=800000, 64 -> 128 -> 64, fp32.
//   h   = relu(mean_agg(x) @ W1_l + b1 + x @ W1_r)
//   out = mean_agg(h) @ W2_l + b2 + h @ W2_r
// R3 (resubmit; prior round was an infra failure): split latency-bound
// gather from compute-bound dense. Gather kernel is lean (low VGPR, high
// occupancy) with 4-edge-parallel float4 loads per wave.
// Linearity: mean_agg(h)@W2_l = agg(h@W2_l)/cnt -> layer 2 gathers p = h@W2_l.

#define SCAN_B 256

// ---------------- CSR build ----------------
__global__ __launch_bounds__(256) void k_hist(const int* __restrict__ dst,
                                              int* __restrict__ deg, int E) {
  int e = blockIdx.x * blockDim.x + threadIdx.x;
  if (e < E) atomicAdd(&deg[dst[e]], 1);
}

__global__ __launch_bounds__(SCAN_B) void k_scan1(const int* __restrict__ deg,
                                                  int* __restrict__ rowptr,
                                                  int* __restrict__ bsum,
                                                  int N) {
  __shared__ int s[SCAN_B];
  int t = threadIdx.x;
  int gid = blockIdx.x * SCAN_B + t;
  int v = (gid < N) ? deg[gid] : 0;
  s[t] = v;
  __syncthreads();
  for (int off = 1; off < SCAN_B; off <<= 1) {
    int add = (t >= off) ? s[t - off] : 0;
    __syncthreads();
    s[t] += add;
    __syncthreads();
  }
  if (gid < N) rowptr[gid] = s[t] - v;
  if (t == SCAN_B - 1) bsum[blockIdx.x] = s[t];
}

__global__ __launch_bounds__(SCAN_B) void k_scan2(int* __restrict__ bsum,
                                                  int* __restrict__ rowptr,
                                                  int NB, int N) {
  __shared__ int s[SCAN_B];
  int t = threadIdx.x;
  int v = (t < NB) ? bsum[t] : 0;
  s[t] = v;
  __syncthreads();
  for (int off = 1; off < SCAN_B; off <<= 1) {
    int add = (t >= off) ? s[t - off] : 0;
    __syncthreads();
    s[t] += add;
    __syncthreads();
  }
  if (t < NB) bsum[t] = s[t] - v;
  if (t == NB - 1) rowptr[N] = s[t];
}

__global__ __launch_bounds__(SCAN_B) void k_scan3(int* __restrict__ rowptr,
                                                  const int* __restrict__ bsum,
                                                  int* __restrict__ pos,
                                                  int N) {
  int gid = blockIdx.x * SCAN_B + threadIdx.x;
  if (gid < N) {
    int r = rowptr[gid] + bsum[blockIdx.x];
    rowptr[gid] = r;
    pos[gid] = r;
  }
}

__global__ __launch_bounds__(256) void k_fill(const int* __restrict__ src,
                                              const int* __restrict__ dst,
                                              int* __restrict__ pos,
                                              int* __restrict__ colsrc, int E) {
  int e = blockIdx.x * blockDim.x + threadIdx.x;
  if (e >= E) return;
  int slot = atomicAdd(&pos[dst[e]], 1);
  colsrc[slot] = src[e];
}

// ---------------------------------------------------------------------------
// gather: mean[node][c] = sum_{e in CSR row} feat[colsrc[e]][c] / max(deg,1).
// 4 waves/block, one node per wave. Within a wave: 4 edge-groups x 16 lanes
// x float4 -> 4 independent 256B row loads in flight; shfl_xor reduce.
// ---------------------------------------------------------------------------
__global__ __launch_bounds__(256) void k_gather(
    const float* __restrict__ feat, const int* __restrict__ rowptr,
    const int* __restrict__ colsrc, float* __restrict__ mean, int N) {
  int wave = threadIdx.x >> 6;
  int lane = threadIdx.x & 63;
  int node = blockIdx.x * 4 + wave;
  if (node >= N) return;
  int beg = rowptr[node], end = rowptr[node + 1];
  int eg = lane >> 4;          // edge group 0..3
  int c4 = (lane & 15) << 2;   // column offset 0,4,...,60
  float4 s = make_float4(0.f, 0.f, 0.f, 0.f);
  for (int e = beg + eg; e < end; e += 4) {
    const float4 v =
        *reinterpret_cast<const float4*>(feat + (size_t)colsrc[e] * 64 + c4);
    s.x += v.x;
    s.y += v.y;
    s.z += v.z;
    s.w += v.w;
  }
#pragma unroll
  for (int m = 16; m <= 32; m <<= 1) {
    s.x += __shfl_xor(s.x, m);
    s.y += __shfl_xor(s.y, m);
    s.z += __shfl_xor(s.z, m);
    s.w += __shfl_xor(s.w, m);
  }
  if (eg == 0) {
    float r = 1.f / fmaxf((float)(end - beg), 1.f);
    float4 o = make_float4(s.x * r, s.y * r, s.z * r, s.w * r);
    *reinterpret_cast<float4*>(mean + (size_t)node * 64 + c4) = o;
  }
}

// ---------------------------------------------------------------------------
// dense1: per 4 nodes (128 threads):
//   h = relu(mean@W1l + b1 + x@W1r), p = h@W2l. All LDS reads wave-uniform.
// ---------------------------------------------------------------------------
__global__ __launch_bounds__(128) void k_dense1(
    const float* __restrict__ x, const float* __restrict__ mean1,
    const float* __restrict__ W1l, const float* __restrict__ b1,
    const float* __restrict__ W1r, const float* __restrict__ W2l,
    float* __restrict__ h, float* __restrict__ p, int N) {
  int i0 = blockIdx.x * 4;
  int j = threadIdx.x;  // 0..127
  int jc = j & 63;
  __shared__ float ms[4][64];
  __shared__ float xs[4][64];
  __shared__ float hs[4][128];
  for (int n = j >> 6; n < 4; n += 2) {
    int node = i0 + n;
    if (node < N) {
      ms[n][jc] = mean1[(size_t)node * 64 + jc];
      xs[n][jc] = x[(size_t)node * 64 + jc];
    }
  }
  __syncthreads();

  float a0 = b1[j], a1 = a0, a2 = a0, a3 = a0;
#pragma unroll
  for (int k = 0; k < 64; ++k) {
    float wl = W1l[k * 128 + j];
    float wr = W1r[k * 128 + j];
    a0 += ms[0][k] * wl + xs[0][k] * wr;
    a1 += ms[1][k] * wl + xs[1][k] * wr;
    a2 += ms[2][k] * wl + xs[2][k] * wr;
    a3 += ms[3][k] * wl + xs[3][k] * wr;
  }
  a0 = fmaxf(a0, 0.f);
  a1 = fmaxf(a1, 0.f);
  a2 = fmaxf(a2, 0.f);
  a3 = fmaxf(a3, 0.f);
  hs[0][j] = a0;
  hs[1][j] = a1;
  hs[2][j] = a2;
  hs[3][j] = a3;
  if (i0 + 0 < N) h[(size_t)(i0 + 0) * 128 + j] = a0;
  if (i0 + 1 < N) h[(size_t)(i0 + 1) * 128 + j] = a1;
  if (i0 + 2 < N) h[(size_t)(i0 + 2) * 128 + j] = a2;
  if (i0 + 3 < N) h[(size_t)(i0 + 3) * 128 + j] = a3;
  __syncthreads();

  for (int np = 0; np < 2; ++np) {
    int n = np * 2 + (j >> 6);  // wave-uniform
    int node = i0 + n;
    if (node >= N) continue;
    float a = 0.f;
#pragma unroll
    for (int k = 0; k < 128; ++k) a += hs[n][k] * W2l[k * 64 + jc];
    p[(size_t)node * 64 + jc] = a;
  }
}

// ---------------------------------------------------------------------------
// dense2: out = mean2 + b2 + h@W2r. 4 nodes/block, 256 threads (node=j>>6,
// wave-uniform -> LDS broadcast).
// ---------------------------------------------------------------------------
__global__ __launch_bounds__(256) void k_dense2(
    const float* __restrict__ h, const float* __restrict__ mean2,
    const float* __restrict__ W2r, const float* __restrict__ b2,
    float* __restrict__ out, int N) {
  int i0 = blockIdx.x * 4;
  int j = threadIdx.x;
  int n = j >> 6;
  int jc = j & 63;
  __shared__ float hs[4][128];
  for (int idx = j; idx < 512; idx += 256) {
    int node = i0 + (idx >> 7);
    if (node < N) hs[idx >> 7][idx & 127] = h[(size_t)node * 128 + (idx & 127)];
  }
  __syncthreads();
  int node = i0 + n;
  if (node >= N) return;
  float a = mean2[(size_t)node * 64 + jc] + b2[jc];
#pragma unroll
  for (int k = 0; k < 128; ++k) a += hs[n][k] * W2r[k * 64 + jc];
  out[(size_t)node * 64 + jc] = a;
}

extern "C" void kernel_launch(void* const* d_in, const int* in_sizes, int n_in,
                              void* d_out, int out_size, void* d_ws,
                              size_t ws_size, hipStream_t stream) {
  const float* x = (const float*)d_in[0];
  const int* ei = (const int*)d_in[1];
  const float* W1l = (const float*)d_in[2];
  const float* b1 = (const float*)d_in[3];
  const float* W1r = (const float*)d_in[4];
  const float* W2l = (const float*)d_in[5];
  const float* b2 = (const float*)d_in[6];
  const float* W2r = (const float*)d_in[7];
  float* out = (float*)d_out;

  const int N = in_sizes[0] / 64;  // 50000
  const int E = in_sizes[1] / 2;   // 800000
  const int* src = ei;
  const int* dst = ei + E;

  // ws: int deg[N] | rowptr[N+1] | pos[N] | bsum[256] | colsrc[E]
  //   | float mean[N*64] (shared by both layers) | h[N*128] | p[N*64]
  int* deg = (int*)d_ws;
  int* rowptr = deg + N;
  int* pos = rowptr + (N + 1);
  int* bsum = pos + N;
  int* colsrc = bsum + 256;
  float* mean = (float*)(colsrc + E);
  float* h = mean + (size_t)N * 64;
  float* p = h + (size_t)N * 128;

  const int NB = (N + SCAN_B - 1) / SCAN_B;

  hipMemsetAsync(deg, 0, (size_t)N * sizeof(int), stream);
  k_hist<<<(E + 255) / 256, 256, 0, stream>>>(dst, deg, E);
  k_scan1<<<NB, SCAN_B, 0, stream>>>(deg, rowptr, bsum, N);
  k_scan2<<<1, SCAN_B, 0, stream>>>(bsum, rowptr, NB, N);
  k_scan3<<<NB, SCAN_B, 0, stream>>>(rowptr, bsum, pos, N);
  k_fill<<<(E + 255) / 256, 256, 0, stream>>>(src, dst, pos, colsrc, E);

  int nblk = (N + 3) / 4;  // 12500
  k_gather<<<nblk, 256, 0, stream>>>(x, rowptr, colsrc, mean, N);
  k_dense1<<<nblk, 128, 0, stream>>>(x, mean, W1l, b1, W1r, W2l, h, p, N);
  k_gather<<<nblk, 256, 0, stream>>>(p, rowptr, colsrc, mean, N);
  k_dense2<<<nblk, 256, 0, stream>>>(h, mean, W2r, b2, out, N);
}

// Round 5
// 461.462 us; speedup vs baseline: 3.5510x; 1.0014x over previous
//
#include <hip/hip_runtime.h>

// GraphSAGE 2-layer, N=50000, E=800000, 64 -> 128 -> 64, fp32.
//   h   = relu(mean_agg(x) @ W1_l + b1 + x @ W1_r)
//   out = mean_agg(h) @ W2_l + b2 + h @ W2_r
// R5: dense kernels register-tiled: 16 nodes/block, 8 accumulators/thread,
// 64 FMAs per 8 weight loads (was 8 per 2), node features via wave-uniform
// LDS b128 broadcasts. Gather/CSR unchanged from R4.
// Linearity: mean_agg(h)@W2_l = agg(h@W2_l)/cnt -> layer 2 gathers p = h@W2_l.

#define SCAN_B 256

// ---------------- CSR build ----------------
__global__ __launch_bounds__(256) void k_hist(const int* __restrict__ dst,
                                              int* __restrict__ deg, int E) {
  int e = blockIdx.x * blockDim.x + threadIdx.x;
  if (e < E) atomicAdd(&deg[dst[e]], 1);
}

__global__ __launch_bounds__(SCAN_B) void k_scan1(const int* __restrict__ deg,
                                                  int* __restrict__ rowptr,
                                                  int* __restrict__ bsum,
                                                  int N) {
  __shared__ int s[SCAN_B];
  int t = threadIdx.x;
  int gid = blockIdx.x * SCAN_B + t;
  int v = (gid < N) ? deg[gid] : 0;
  s[t] = v;
  __syncthreads();
  for (int off = 1; off < SCAN_B; off <<= 1) {
    int add = (t >= off) ? s[t - off] : 0;
    __syncthreads();
    s[t] += add;
    __syncthreads();
  }
  if (gid < N) rowptr[gid] = s[t] - v;
  if (t == SCAN_B - 1) bsum[blockIdx.x] = s[t];
}

__global__ __launch_bounds__(SCAN_B) void k_scan2(int* __restrict__ bsum,
                                                  int* __restrict__ rowptr,
                                                  int NB, int N) {
  __shared__ int s[SCAN_B];
  int t = threadIdx.x;
  int v = (t < NB) ? bsum[t] : 0;
  s[t] = v;
  __syncthreads();
  for (int off = 1; off < SCAN_B; off <<= 1) {
    int add = (t >= off) ? s[t - off] : 0;
    __syncthreads();
    s[t] += add;
    __syncthreads();
  }
  if (t < NB) bsum[t] = s[t] - v;
  if (t == NB - 1) rowptr[N] = s[t];
}

__global__ __launch_bounds__(SCAN_B) void k_scan3(int* __restrict__ rowptr,
                                                  const int* __restrict__ bsum,
                                                  int* __restrict__ pos,
                                                  int N) {
  int gid = blockIdx.x * SCAN_B + threadIdx.x;
  if (gid < N) {
    int r = rowptr[gid] + bsum[blockIdx.x];
    rowptr[gid] = r;
    pos[gid] = r;
  }
}

__global__ __launch_bounds__(256) void k_fill(const int* __restrict__ src,
                                              const int* __restrict__ dst,
                                              int* __restrict__ pos,
                                              int* __restrict__ colsrc, int E) {
  int e = blockIdx.x * blockDim.x + threadIdx.x;
  if (e >= E) return;
  int slot = atomicAdd(&pos[dst[e]], 1);
  colsrc[slot] = src[e];
}

// ---------------------------------------------------------------------------
// gather: mean[node][c] = sum_{CSR row} feat[colsrc[e]][c] / max(deg,1).
// 4 waves/block, one node/wave, 4 edge-groups x 16 lanes x float4.
// ---------------------------------------------------------------------------
__global__ __launch_bounds__(256) void k_gather(
    const float* __restrict__ feat, const int* __restrict__ rowptr,
    const int* __restrict__ colsrc, float* __restrict__ mean, int N) {
  int wave = threadIdx.x >> 6;
  int lane = threadIdx.x & 63;
  int node = blockIdx.x * 4 + wave;
  if (node >= N) return;
  int beg = rowptr[node], end = rowptr[node + 1];
  int eg = lane >> 4;
  int c4 = (lane & 15) << 2;
  float4 s = make_float4(0.f, 0.f, 0.f, 0.f);
  for (int e = beg + eg; e < end; e += 4) {
    const float4 v =
        *reinterpret_cast<const float4*>(feat + (size_t)colsrc[e] * 64 + c4);
    s.x += v.x;
    s.y += v.y;
    s.z += v.z;
    s.w += v.w;
  }
#pragma unroll
  for (int m = 16; m <= 32; m <<= 1) {
    s.x += __shfl_xor(s.x, m);
    s.y += __shfl_xor(s.y, m);
    s.z += __shfl_xor(s.z, m);
    s.w += __shfl_xor(s.w, m);
  }
  if (eg == 0) {
    float r = 1.f / fmaxf((float)(end - beg), 1.f);
    float4 o = make_float4(s.x * r, s.y * r, s.z * r, s.w * r);
    *reinterpret_cast<float4*>(mean + (size_t)node * 64 + c4) = o;
  }
}

// ---------------------------------------------------------------------------
// dense1: 16 nodes/block, 256 threads.
// Phase 1: thread (j=tid&127, g=tid>>7) computes h[node][j] for 8 nodes
//   (g*8..g*8+7): 8 acc chains, 8 weight loads per 4-k step feed 64 FMAs.
// Phase 2: thread (jc=tid&63, g2=tid>>6) computes p[node][jc] for 4 nodes.
// ---------------------------------------------------------------------------
__global__ __launch_bounds__(256) void k_dense1(
    const float* __restrict__ x, const float* __restrict__ mean1,
    const float* __restrict__ W1l, const float* __restrict__ b1,
    const float* __restrict__ W1r, const float* __restrict__ W2l,
    float* __restrict__ h, float* __restrict__ p, int N) {
  int i0 = blockIdx.x * 16;
  int tid = threadIdx.x;
  __shared__ float ms[16][64];
  __shared__ float xs[16][64];
  __shared__ float hs[16][128];

  // stage: thread t loads float4 for node t>>4, cols (t&15)*4
  {
    int n = tid >> 4;
    int c4 = (tid & 15) << 2;
    int node = i0 + n;
    if (node < N) {
      *(float4*)&ms[n][c4] =
          *(const float4*)&mean1[(size_t)node * 64 + c4];
      *(float4*)&xs[n][c4] = *(const float4*)&x[(size_t)node * 64 + c4];
    } else {
      float4 z = make_float4(0.f, 0.f, 0.f, 0.f);
      *(float4*)&ms[n][c4] = z;
      *(float4*)&xs[n][c4] = z;
    }
  }
  __syncthreads();

  int j = tid & 127;
  int g = tid >> 7;  // wave-uniform: 0 or 1
  float acc[8];
  {
    float bj = b1[j];
#pragma unroll
    for (int n = 0; n < 8; ++n) acc[n] = bj;
  }
  for (int k0 = 0; k0 < 64; k0 += 4) {
    float wl0 = W1l[(k0 + 0) * 128 + j];
    float wl1 = W1l[(k0 + 1) * 128 + j];
    float wl2 = W1l[(k0 + 2) * 128 + j];
    float wl3 = W1l[(k0 + 3) * 128 + j];
    float wr0 = W1r[(k0 + 0) * 128 + j];
    float wr1 = W1r[(k0 + 1) * 128 + j];
    float wr2 = W1r[(k0 + 2) * 128 + j];
    float wr3 = W1r[(k0 + 3) * 128 + j];
#pragma unroll
    for (int n = 0; n < 8; ++n) {
      float4 m4 = *(const float4*)&ms[g * 8 + n][k0];
      float4 x4 = *(const float4*)&xs[g * 8 + n][k0];
      acc[n] += m4.x * wl0 + m4.y * wl1 + m4.z * wl2 + m4.w * wl3 +
                x4.x * wr0 + x4.y * wr1 + x4.z * wr2 + x4.w * wr3;
    }
  }
#pragma unroll
  for (int n = 0; n < 8; ++n) {
    float v = fmaxf(acc[n], 0.f);
    int node = i0 + g * 8 + n;
    hs[g * 8 + n][j] = v;
    if (node < N) h[(size_t)node * 128 + j] = v;
  }
  __syncthreads();

  // phase 2: p = hs @ W2l
  int jc = tid & 63;
  int g2 = tid >> 6;  // wave-half; n-index wave-uniform enough for broadcast
  float pacc[4] = {0.f, 0.f, 0.f, 0.f};
  for (int k0 = 0; k0 < 128; k0 += 4) {
    float w0 = W2l[(k0 + 0) * 64 + jc];
    float w1 = W2l[(k0 + 1) * 64 + jc];
    float w2 = W2l[(k0 + 2) * 64 + jc];
    float w3 = W2l[(k0 + 3) * 64 + jc];
#pragma unroll
    for (int n = 0; n < 4; ++n) {
      float4 h4 = *(const float4*)&hs[g2 * 4 + n][k0];
      pacc[n] += h4.x * w0 + h4.y * w1 + h4.z * w2 + h4.w * w3;
    }
  }
#pragma unroll
  for (int n = 0; n < 4; ++n) {
    int node = i0 + g2 * 4 + n;
    if (node < N) p[(size_t)node * 64 + jc] = pacc[n];
  }
}

// ---------------------------------------------------------------------------
// dense2: 16 nodes/block, 256 threads. out = mean2 + b2 + h@W2r.
// ---------------------------------------------------------------------------
__global__ __launch_bounds__(256) void k_dense2(
    const float* __restrict__ h, const float* __restrict__ mean2,
    const float* __restrict__ W2r, const float* __restrict__ b2,
    float* __restrict__ out, int N) {
  int i0 = blockIdx.x * 16;
  int tid = threadIdx.x;
  __shared__ float hs[16][128];
  {
    int n = tid >> 4;
    int c8 = (tid & 15) << 3;
    int node = i0 + n;
    if (node < N) {
      *(float4*)&hs[n][c8] = *(const float4*)&h[(size_t)node * 128 + c8];
      *(float4*)&hs[n][c8 + 4] =
          *(const float4*)&h[(size_t)node * 128 + c8 + 4];
    }
  }
  __syncthreads();

  int jc = tid & 63;
  int g2 = tid >> 6;
  float acc[4] = {0.f, 0.f, 0.f, 0.f};
  for (int k0 = 0; k0 < 128; k0 += 4) {
    float w0 = W2r[(k0 + 0) * 64 + jc];
    float w1 = W2r[(k0 + 1) * 64 + jc];
    float w2 = W2r[(k0 + 2) * 64 + jc];
    float w3 = W2r[(k0 + 3) * 64 + jc];
#pragma unroll
    for (int n = 0; n < 4; ++n) {
      float4 h4 = *(const float4*)&hs[g2 * 4 + n][k0];
      acc[n] += h4.x * w0 + h4.y * w1 + h4.z * w2 + h4.w * w3;
    }
  }
  float bj = b2[jc];
#pragma unroll
  for (int n = 0; n < 4; ++n) {
    int node = i0 + g2 * 4 + n;
    if (node < N)
      out[(size_t)node * 64 + jc] =
          mean2[(size_t)node * 64 + jc] + bj + acc[n];
  }
}

extern "C" void kernel_launch(void* const* d_in, const int* in_sizes, int n_in,
                              void* d_out, int out_size, void* d_ws,
                              size_t ws_size, hipStream_t stream) {
  const float* x = (const float*)d_in[0];
  const int* ei = (const int*)d_in[1];
  const float* W1l = (const float*)d_in[2];
  const float* b1 = (const float*)d_in[3];
  const float* W1r = (const float*)d_in[4];
  const float* W2l = (const float*)d_in[5];
  const float* b2 = (const float*)d_in[6];
  const float* W2r = (const float*)d_in[7];
  float* out = (float*)d_out;

  const int N = in_sizes[0] / 64;  // 50000
  const int E = in_sizes[1] / 2;   // 800000
  const int* src = ei;
  const int* dst = ei + E;

  // ws: int deg[N] | rowptr[N+1] | pos[N] | bsum[256] | colsrc[E]
  //   | float mean[N*64] (shared by both layers) | h[N*128] | p[N*64]
  int* deg = (int*)d_ws;
  int* rowptr = deg + N;
  int* pos = rowptr + (N + 1);
  int* bsum = pos + N;
  int* colsrc = bsum + 256;
  float* mean = (float*)(colsrc + E);
  float* h = mean + (size_t)N * 64;
  float* p = h + (size_t)N * 128;

  const int NB = (N + SCAN_B - 1) / SCAN_B;

  hipMemsetAsync(deg, 0, (size_t)N * sizeof(int), stream);
  k_hist<<<(E + 255) / 256, 256, 0, stream>>>(dst, deg, E);
  k_scan1<<<NB, SCAN_B, 0, stream>>>(deg, rowptr, bsum, N);
  k_scan2<<<1, SCAN_B, 0, stream>>>(bsum, rowptr, NB, N);
  k_scan3<<<NB, SCAN_B, 0, stream>>>(rowptr, bsum, pos, N);
  k_fill<<<(E + 255) / 256, 256, 0, stream>>>(src, dst, pos, colsrc, E);

  int nblk4 = (N + 3) / 4;    // gather blocks
  int nblk16 = (N + 15) / 16; // dense blocks
  k_gather<<<nblk4, 256, 0, stream>>>(x, rowptr, colsrc, mean, N);
  k_dense1<<<nblk16, 256, 0, stream>>>(x, mean, W1l, b1, W1r, W2l, h, p, N);
  k_gather<<<nblk4, 256, 0, stream>>>(p, rowptr, colsrc, mean, N);
  k_dense2<<<nblk16, 256, 0, stream>>>(h, mean, W2r, b2, out, N);
}

// Round 6
// 321.145 us; speedup vs baseline: 5.1025x; 1.4369x over previous
//
#include <hip/hip_runtime.h>

// GraphSAGE 2-layer, N=50000, E=800000, 64 -> 128 -> 64, fp32.
//   h   = relu(mean_agg(x) @ W1_l + b1 + x @ W1_r)
//   out = mean_agg(h) @ W2_l + b2 + h @ W2_r
// R6: dense fully fused + 4x4 register tiling.
//   k_dense1: 32 nodes/block; phase1 h (4n x 4j tile/thread, weights via
//   coalesced global float4, features via LDS broadcast), phase2 waves 0-1
//   compute p=h@W2_l while waves 2-3 compute q=h@W2_r from LDS hs (pad 132).
//   h never touches global (saves 51MB). dense2 -> elementwise k_final.
// Linearity: mean_agg(h)@W2_l = agg(h@W2_l)/cnt -> layer 2 gathers p.

#define SCAN_B 256

#define FMA4(acc, f, w0, w1, w2, w3)                          \
  acc.x += f.x * w0.x + f.y * w1.x + f.z * w2.x + f.w * w3.x; \
  acc.y += f.x * w0.y + f.y * w1.y + f.z * w2.y + f.w * w3.y; \
  acc.z += f.x * w0.z + f.y * w1.z + f.z * w2.z + f.w * w3.z; \
  acc.w += f.x * w0.w + f.y * w1.w + f.z * w2.w + f.w * w3.w;

// ---------------- CSR build ----------------
__global__ __launch_bounds__(256) void k_hist(const int* __restrict__ dst,
                                              int* __restrict__ deg, int E) {
  int e = blockIdx.x * blockDim.x + threadIdx.x;
  if (e < E) atomicAdd(&deg[dst[e]], 1);
}

__global__ __launch_bounds__(SCAN_B) void k_scan1(const int* __restrict__ deg,
                                                  int* __restrict__ rowptr,
                                                  int* __restrict__ bsum,
                                                  int N) {
  __shared__ int s[SCAN_B];
  int t = threadIdx.x;
  int gid = blockIdx.x * SCAN_B + t;
  int v = (gid < N) ? deg[gid] : 0;
  s[t] = v;
  __syncthreads();
  for (int off = 1; off < SCAN_B; off <<= 1) {
    int add = (t >= off) ? s[t - off] : 0;
    __syncthreads();
    s[t] += add;
    __syncthreads();
  }
  if (gid < N) rowptr[gid] = s[t] - v;
  if (t == SCAN_B - 1) bsum[blockIdx.x] = s[t];
}

__global__ __launch_bounds__(SCAN_B) void k_scan2(int* __restrict__ bsum,
                                                  int* __restrict__ rowptr,
                                                  int NB, int N) {
  __shared__ int s[SCAN_B];
  int t = threadIdx.x;
  int v = (t < NB) ? bsum[t] : 0;
  s[t] = v;
  __syncthreads();
  for (int off = 1; off < SCAN_B; off <<= 1) {
    int add = (t >= off) ? s[t - off] : 0;
    __syncthreads();
    s[t] += add;
    __syncthreads();
  }
  if (t < NB) bsum[t] = s[t] - v;
  if (t == NB - 1) rowptr[N] = s[t];
}

__global__ __launch_bounds__(SCAN_B) void k_scan3(int* __restrict__ rowptr,
                                                  const int* __restrict__ bsum,
                                                  int* __restrict__ pos,
                                                  int N) {
  int gid = blockIdx.x * SCAN_B + threadIdx.x;
  if (gid < N) {
    int r = rowptr[gid] + bsum[blockIdx.x];
    rowptr[gid] = r;
    pos[gid] = r;
  }
}

__global__ __launch_bounds__(256) void k_fill(const int* __restrict__ src,
                                              const int* __restrict__ dst,
                                              int* __restrict__ pos,
                                              int* __restrict__ colsrc, int E) {
  int e = blockIdx.x * blockDim.x + threadIdx.x;
  if (e >= E) return;
  int slot = atomicAdd(&pos[dst[e]], 1);
  colsrc[slot] = src[e];
}

// ---------------------------------------------------------------------------
// gather: mean[node][c] = sum_{CSR row} feat[colsrc[e]][c] / max(deg,1).
// 4 waves/block, one node/wave, 4 edge-groups x 16 lanes x float4.
// ---------------------------------------------------------------------------
__global__ __launch_bounds__(256) void k_gather(
    const float* __restrict__ feat, const int* __restrict__ rowptr,
    const int* __restrict__ colsrc, float* __restrict__ mean, int N) {
  int wave = threadIdx.x >> 6;
  int lane = threadIdx.x & 63;
  int node = blockIdx.x * 4 + wave;
  if (node >= N) return;
  int beg = rowptr[node], end = rowptr[node + 1];
  int eg = lane >> 4;
  int c4 = (lane & 15) << 2;
  float4 s = make_float4(0.f, 0.f, 0.f, 0.f);
  for (int e = beg + eg; e < end; e += 4) {
    const float4 v =
        *reinterpret_cast<const float4*>(feat + (size_t)colsrc[e] * 64 + c4);
    s.x += v.x;
    s.y += v.y;
    s.z += v.z;
    s.w += v.w;
  }
#pragma unroll
  for (int m = 16; m <= 32; m <<= 1) {
    s.x += __shfl_xor(s.x, m);
    s.y += __shfl_xor(s.y, m);
    s.z += __shfl_xor(s.z, m);
    s.w += __shfl_xor(s.w, m);
  }
  if (eg == 0) {
    float r = 1.f / fmaxf((float)(end - beg), 1.f);
    float4 o = make_float4(s.x * r, s.y * r, s.z * r, s.w * r);
    *reinterpret_cast<float4*>(mean + (size_t)node * 64 + c4) = o;
  }
}

// ---------------------------------------------------------------------------
// dense1: 32 nodes/block, 256 threads.
// Phase 1: thread (jt=tid&31, nt=tid>>5) computes h[n0..n0+3][j0..j0+3]
//   (4x4 reg tile): per 4-k step, 8 global float4 weight loads + 8 LDS b128
//   feature broadcasts feed 128 FMAs. h -> LDS only (pad 132).
// Phase 2: waves 0-1 -> p = h@W2l, waves 2-3 -> q = h@W2r (4x4 tiles).
// ---------------------------------------------------------------------------
__global__ __launch_bounds__(256) void k_dense1(
    const float* __restrict__ x, const float* __restrict__ mean1,
    const float* __restrict__ W1l, const float* __restrict__ b1,
    const float* __restrict__ W1r, const float* __restrict__ W2l,
    const float* __restrict__ W2r, float* __restrict__ p,
    float* __restrict__ q, int N) {
  int i0 = blockIdx.x * 32;
  int tid = threadIdx.x;
  __shared__ float ms[32][64];
  __shared__ float xs[32][64];
  __shared__ float hs[32][132];  // pad: row stride 132 (528B, 16B-aligned)

  // stage features: 32 nodes x 64 cols, 2 float4 per thread per array
  for (int t = tid; t < 512; t += 256) {
    int n = t >> 4;
    int c4 = (t & 15) << 2;
    int node = i0 + n;
    float4 zm, zx;
    if (node < N) {
      zm = *(const float4*)&mean1[(size_t)node * 64 + c4];
      zx = *(const float4*)&x[(size_t)node * 64 + c4];
    } else {
      zm = make_float4(0.f, 0.f, 0.f, 0.f);
      zx = zm;
    }
    *(float4*)&ms[n][c4] = zm;
    *(float4*)&xs[n][c4] = zx;
  }
  __syncthreads();

  // ---- phase 1: h tile ----
  int jt = tid & 31;
  int j0 = jt << 2;
  int nt = tid >> 5;
  int n0 = nt << 2;
  float4 acc[4];
  {
    float4 bj = *(const float4*)&b1[j0];
    acc[0] = bj; acc[1] = bj; acc[2] = bj; acc[3] = bj;
  }
  for (int k0 = 0; k0 < 64; k0 += 4) {
    float4 wl[4], wr[4];
#pragma unroll
    for (int kk = 0; kk < 4; ++kk) {
      wl[kk] = *(const float4*)&W1l[(size_t)(k0 + kk) * 128 + j0];
      wr[kk] = *(const float4*)&W1r[(size_t)(k0 + kk) * 128 + j0];
    }
#pragma unroll
    for (int n = 0; n < 4; ++n) {
      float4 m4 = *(const float4*)&ms[n0 + n][k0];
      float4 x4 = *(const float4*)&xs[n0 + n][k0];
      FMA4(acc[n], m4, wl[0], wl[1], wl[2], wl[3]);
      FMA4(acc[n], x4, wr[0], wr[1], wr[2], wr[3]);
    }
  }
#pragma unroll
  for (int n = 0; n < 4; ++n) {
    float4 v = acc[n];
    v.x = fmaxf(v.x, 0.f);
    v.y = fmaxf(v.y, 0.f);
    v.z = fmaxf(v.z, 0.f);
    v.w = fmaxf(v.w, 0.f);
    *(float4*)&hs[n0 + n][j0] = v;
  }
  __syncthreads();

  // ---- phase 2: p = hs@W2l (waves 0-1), q = hs@W2r (waves 2-3) ----
  const float* W = (tid < 128) ? W2l : W2r;
  float* ob = (tid < 128) ? p : q;
  int t2 = tid & 127;
  int jt2 = t2 & 15;
  int jj0 = jt2 << 2;
  int nt2 = t2 >> 4;
  int nn0 = nt2 << 2;
  float4 pa[4];
  pa[0] = make_float4(0.f, 0.f, 0.f, 0.f);
  pa[1] = pa[0]; pa[2] = pa[0]; pa[3] = pa[0];
  for (int k0 = 0; k0 < 128; k0 += 4) {
    float4 w[4];
#pragma unroll
    for (int kk = 0; kk < 4; ++kk)
      w[kk] = *(const float4*)&W[(size_t)(k0 + kk) * 64 + jj0];
#pragma unroll
    for (int n = 0; n < 4; ++n) {
      float4 h4 = *(const float4*)&hs[nn0 + n][k0];
      FMA4(pa[n], h4, w[0], w[1], w[2], w[3]);
    }
  }
#pragma unroll
  for (int n = 0; n < 4; ++n) {
    int node = i0 + nn0 + n;
    if (node < N) *(float4*)&ob[(size_t)node * 64 + jj0] = pa[n];
  }
}

// ---------------------------------------------------------------------------
// final: out = mean2 + b2 + q, elementwise float4.
// ---------------------------------------------------------------------------
__global__ __launch_bounds__(256) void k_final(const float* __restrict__ mean2,
                                               const float* __restrict__ q,
                                               const float* __restrict__ b2,
                                               float* __restrict__ out,
                                               int total4) {
  int i = blockIdx.x * blockDim.x + threadIdx.x;
  if (i >= total4) return;
  float4 m = *(const float4*)&mean2[(size_t)i * 4];
  float4 qq = *(const float4*)&q[(size_t)i * 4];
  float4 b = *(const float4*)&b2[(i & 15) << 2];
  float4 o = make_float4(m.x + qq.x + b.x, m.y + qq.y + b.y,
                         m.z + qq.z + b.z, m.w + qq.w + b.w);
  *(float4*)&out[(size_t)i * 4] = o;
}

extern "C" void kernel_launch(void* const* d_in, const int* in_sizes, int n_in,
                              void* d_out, int out_size, void* d_ws,
                              size_t ws_size, hipStream_t stream) {
  const float* x = (const float*)d_in[0];
  const int* ei = (const int*)d_in[1];
  const float* W1l = (const float*)d_in[2];
  const float* b1 = (const float*)d_in[3];
  const float* W1r = (const float*)d_in[4];
  const float* W2l = (const float*)d_in[5];
  const float* b2 = (const float*)d_in[6];
  const float* W2r = (const float*)d_in[7];
  float* out = (float*)d_out;

  const int N = in_sizes[0] / 64;  // 50000
  const int E = in_sizes[1] / 2;   // 800000
  const int* src = ei;
  const int* dst = ei + E;

  // ws: int deg[N] | rowptr[N+1] | pos[N] | bsum[256] | colsrc[E]
  //   | float mean[N*64] | p[N*64] | q[N*64]
  int* deg = (int*)d_ws;
  int* rowptr = deg + N;
  int* pos = rowptr + (N + 1);
  int* bsum = pos + N;
  int* colsrc = bsum + 256;
  float* mean = (float*)(colsrc + E);
  float* p = mean + (size_t)N * 64;
  float* q = p + (size_t)N * 64;

  const int NB = (N + SCAN_B - 1) / SCAN_B;

  hipMemsetAsync(deg, 0, (size_t)N * sizeof(int), stream);
  k_hist<<<(E + 255) / 256, 256, 0, stream>>>(dst, deg, E);
  k_scan1<<<NB, SCAN_B, 0, stream>>>(deg, rowptr, bsum, N);
  k_scan2<<<1, SCAN_B, 0, stream>>>(bsum, rowptr, NB, N);
  k_scan3<<<NB, SCAN_B, 0, stream>>>(rowptr, bsum, pos, N);
  k_fill<<<(E + 255) / 256, 256, 0, stream>>>(src, dst, pos, colsrc, E);

  int nblk4 = (N + 3) / 4;     // gather blocks
  int nblk32 = (N + 31) / 32;  // dense blocks
  k_gather<<<nblk4, 256, 0, stream>>>(x, rowptr, colsrc, mean, N);
  k_dense1<<<nblk32, 256, 0, stream>>>(x, mean, W1l, b1, W1r, W2l, W2r, p, q,
                                       N);
  k_gather<<<nblk4, 256, 0, stream>>>(p, rowptr, colsrc, mean, N);
  int total4 = N * 16;  // N*64/4
  k_final<<<(total4 + 255) / 256, 256, 0, stream>>>(mean, q, b2, out, total4);
}